// Round 4
// baseline (713.871 us; speedup 1.0000x reference)
//
#include <hip/hip_runtime.h>
#include <stdint.h>

#define EPSF 1e-7f
#define MAXTAN 10.0f

typedef __bf16 bf16x8 __attribute__((ext_vector_type(8)));
typedef float floatx4 __attribute__((ext_vector_type(4)));
typedef __attribute__((address_space(3))) void lds_void_t;
typedef __attribute__((address_space(1))) void gbl_void_t;

__device__ __forceinline__ unsigned short f2bf(float x) {
  union { float f; uint32_t u; } v; v.f = x;
  uint32_t u = v.u;
  u += 0x7fffu + ((u >> 16) & 1u);   // RNE
  return (unsigned short)(u >> 16);
}
__device__ __forceinline__ float bf2f(unsigned short h) {
  union { uint32_t u; float f; } v; v.u = ((uint32_t)h) << 16;
  return v.f;
}

// ---------------- dtype sniffer: mode=1 bf16 storage, mode=0 fp32 ----------------
__global__ void k_sniff(const unsigned short* __restrict__ x, int* __restrict__ mode) {
  if (threadIdx.x == 0 && blockIdx.x == 0) {
    int sane = 0;
    for (int i = 0; i < 128; ++i) {
      unsigned short h = x[i];
      int e = (h >> 7) & 0xFF;
      if ((h & 0x7FFF) == 0 || (e >= 96 && e <= 140)) ++sane;
    }
    *mode = (sane >= 120) ? 1 : 0;
  }
}

// ---------------- x prep: convert to bf16, compute logmap scale + x0 ----------------
// sc0[m] = acosh(clip(x0)) / max(||xs||,eps);  x0c[m] = bf16-rounded x0 (as MFMA sees it)
__global__ void k_prep(const void* __restrict__ xv, unsigned short* __restrict__ xb,
                       float* __restrict__ sc0, float* __restrict__ x0c,
                       const int* __restrict__ mode) {
  const int row = blockIdx.x;
  const int tid = threadIdx.x;
  float4 v;
  if (*mode) {
    ushort4 u = ((const ushort4*)((const unsigned short*)xv + (size_t)row * 1024))[tid];
    v.x = bf2f(u.x); v.y = bf2f(u.y); v.z = bf2f(u.z); v.w = bf2f(u.w);
  } else {
    v = ((const float4*)((const float*)xv + (size_t)row * 1024))[tid];
  }
  ushort4 o;
  o.x = f2bf(v.x); o.y = f2bf(v.y); o.z = f2bf(v.z); o.w = f2bf(v.w);
  ((ushort4*)(xb + (size_t)row * 1024))[tid] = o;

  float s = v.x * v.x + v.y * v.y + v.z * v.z + v.w * v.w;
  if (tid == 0) s -= v.x * v.x;          // exclude time coordinate
  for (int off = 32; off; off >>= 1) s += __shfl_down(s, off, 64);
  __shared__ float red[4];
  if ((tid & 63) == 0) red[tid >> 6] = s;
  __syncthreads();
  if (tid == 0) {
    s = red[0] + red[1] + red[2] + red[3];
    float ns = fmaxf(sqrtf(s), EPSF);
    float d = acoshf(fmaxf(v.x, 1.0f + EPSF));
    sc0[row] = d / ns;
    x0c[row] = bf2f(o.x);
  }
}

// ---------------- weight convert to bf16 + col0 extraction ----------------
// K8 = K/8 granules per row.
template<int K8>
__global__ void k_cvtw(const void* __restrict__ in, unsigned short* __restrict__ out,
                       const int* __restrict__ mode, int n8, float* __restrict__ c0) {
  int i = blockIdx.x * 256 + threadIdx.x;
  if (i >= n8) return;
  if (*mode) {
    uint4 g = ((const uint4*)in)[i];
    ((uint4*)out)[i] = g;
    if (i % K8 == 0) c0[i / K8] = bf2f((unsigned short)(g.x & 0xFFFFu));
  } else {
    float4 a = ((const float4*)in)[2 * i];
    float4 b = ((const float4*)in)[2 * i + 1];
    ushort4 oa, ob;
    oa.x = f2bf(a.x); oa.y = f2bf(a.y); oa.z = f2bf(a.z); oa.w = f2bf(a.w);
    ob.x = f2bf(b.x); ob.y = f2bf(b.y); ob.z = f2bf(b.z); ob.w = f2bf(b.w);
    ((ushort4*)out)[2 * i] = oa;
    ((ushort4*)out)[2 * i + 1] = ob;
    if (i % K8 == 0) c0[i / K8] = bf2f(oa.x);
  }
}

// ---------------- biases -> f32 (mode-aware; all zeros in practice) ----------------
__global__ void k_cvtb(const void* __restrict__ b1, const void* __restrict__ b2,
                       const void* __restrict__ b3, float* __restrict__ o1,
                       float* __restrict__ o2, float* __restrict__ o3,
                       const int* __restrict__ mode) {
  int i = blockIdx.x * 256 + threadIdx.x;
  int m = *mode;
  if (i < 4096) o1[i] = m ? bf2f(((const unsigned short*)b1)[i]) : ((const float*)b1)[i];
  if (i < 4096) o2[i] = m ? bf2f(((const unsigned short*)b2)[i]) : ((const float*)b2)[i];
  if (i < 1024) o3[i] = m ? bf2f(((const unsigned short*)b3)[i]) : ((const float*)b3)[i];
}

// ---------------- partial-sumsq fold -> scale + col0 grab ----------------
template<int NBLK>
__global__ void k_sc(const float* __restrict__ part, const unsigned short* __restrict__ y,
                     int stride, float* __restrict__ sc, float* __restrict__ c0,
                     float* __restrict__ ssout, int nrows) {
  int i = blockIdx.x * 256 + threadIdx.x;
  if (i >= nrows) return;
  float s = 0.f;
#pragma unroll
  for (int j = 0; j < NBLK; ++j) s += part[(size_t)i * NBLK + j];
  float n = fmaxf(sqrtf(fmaxf(s, 0.f)), EPSF);
  sc[i] = fminf(n, MAXTAN) / n;
  c0[i] = bf2f(y[(size_t)i * stride]);
  if (ssout) ssout[i] = s;
}

// ---------------- final: y3 bf16 + ss3 -> projx(safe_expmap0(y3)) ----------------
__global__ void k_final(const unsigned short* __restrict__ y, const float* __restrict__ ss,
                        void* __restrict__ outv, const int* __restrict__ mode) {
  const int row = blockIdx.x;
  const int tid = threadIdx.x;
  float n = fmaxf(sqrtf(fmaxf(ss[row], 0.f)), EPSF);
  float nc = fminf(n, MAXTAN);
  float a = sinhf(nc) / n;
  ushort4 u = ((const ushort4*)(y + (size_t)row * 1024))[tid];
  float4 o;
  o.x = bf2f(u.x) * a; o.y = bf2f(u.y) * a;
  o.z = bf2f(u.z) * a; o.w = bf2f(u.w) * a;
  if (tid == 0) o.x = coshf(nc);
  if (*mode) {
    ushort4 o16;
    o16.x = f2bf(o.x); o16.y = f2bf(o.y); o16.z = f2bf(o.z); o16.w = f2bf(o.w);
    ((ushort4*)outv)[(size_t)row * 256 + tid] = o16;
  } else {
    ((float4*)outv)[(size_t)row * 256 + tid] = o;
  }
}

// ---------------- NT GEMM, BK=32 (round-2 config), fused rank-1 epilogue ----------------
// y[m,n] = sc[m]*(acc[m,n] - c0f[m]*wc0[n]) + bias[n], stored bf16.
// Per-(row,wave) spatial sumsq partials -> part[gm*NBLK + 2*bx + (wave&1)]  (no atomics).
// LDS swizzle (measured 0 conflicts): granule g of row r holds global granule g ^ ((r>>1)&3).
template<int N, int K, int NBLK>
__global__ __launch_bounds__(256) void k_gemm_bt(
    const unsigned short* __restrict__ A,
    const unsigned short* __restrict__ B,
    const float* __restrict__ bias,
    const float* __restrict__ sc,
    const float* __restrict__ c0f,
    const float* __restrict__ wc0,
    unsigned short* __restrict__ Cb,
    float* __restrict__ part)
{
  __shared__ __align__(16) unsigned short As[128 * 32];
  __shared__ __align__(16) unsigned short Bs[128 * 32];

  const int tid  = threadIdx.x;
  const int wave = tid >> 6;
  const int lane = tid & 63;
  const int quad = lane >> 4;
  const int m16  = lane & 15;

  const int bm = blockIdx.y * 128;
  const int bn = blockIdx.x * 128;

  const int srow = lane >> 2;                                // 0..15 row within chunk
  const int scol = (((lane & 3) ^ ((srow >> 1) & 3)) << 3);  // swizzled granule (elems)

  const int wm = (wave >> 1) << 6;
  const int wn = (wave & 1) << 6;

  const int rsw = ((quad ^ ((m16 >> 1) & 3)) << 3);          // read-side swizzle

  floatx4 acc[4][4];
#pragma unroll
  for (int i = 0; i < 4; ++i)
#pragma unroll
    for (int j = 0; j < 4; ++j)
#pragma unroll
      for (int r = 0; r < 4; ++r) acc[i][j][r] = 0.0f;

  for (int k0 = 0; k0 < K; k0 += 32) {
#pragma unroll
    for (int i = 0; i < 2; ++i) {
      const int c = wave * 2 + i;                            // wave-uniform chunk
      const unsigned short* ga = A + (size_t)(bm + c * 16 + srow) * K + k0 + scol;
      const unsigned short* gb = B + (size_t)(bn + c * 16 + srow) * K + k0 + scol;
      __builtin_amdgcn_global_load_lds((gbl_void_t*)(void*)ga,
                                       (lds_void_t*)(As + c * 512), 16, 0, 0);
      __builtin_amdgcn_global_load_lds((gbl_void_t*)(void*)gb,
                                       (lds_void_t*)(Bs + c * 512), 16, 0, 0);
    }
    __syncthreads();

    bf16x8 af[4], bfg[4];
#pragma unroll
    for (int t = 0; t < 4; ++t) {
      af[t]  = *(const bf16x8*)(As + (wm + t * 16 + m16) * 32 + rsw);
      bfg[t] = *(const bf16x8*)(Bs + (wn + t * 16 + m16) * 32 + rsw);
    }
#pragma unroll
    for (int mt = 0; mt < 4; ++mt)
#pragma unroll
      for (int nt = 0; nt < 4; ++nt)
        acc[mt][nt] = __builtin_amdgcn_mfma_f32_16x16x32_bf16(af[mt], bfg[nt], acc[mt][nt], 0, 0, 0);
    __syncthreads();
  }

  // epilogue: C/D layout col = lane&15, row = quad*4 + r
#pragma unroll
  for (int mt = 0; mt < 4; ++mt) {
#pragma unroll
    for (int r = 0; r < 4; ++r) {
      const int gm = bm + wm + mt * 16 + quad * 4 + r;
      const float scv = sc[gm];
      const float c0v = c0f[gm];
      float sq = 0.f;
#pragma unroll
      for (int nt = 0; nt < 4; ++nt) {
        const int gn = bn + wn + nt * 16 + m16;
        float v = scv * (acc[mt][nt][r] - c0v * wc0[gn]) + bias[gn];
        Cb[(size_t)gm * N + gn] = f2bf(v);
        sq += (gn == 0) ? 0.f : v * v;
      }
      sq += __shfl_xor(sq, 1, 64);
      sq += __shfl_xor(sq, 2, 64);
      sq += __shfl_xor(sq, 4, 64);
      sq += __shfl_xor(sq, 8, 64);
      if (m16 == 0) part[(size_t)gm * NBLK + 2 * blockIdx.x + (wave & 1)] = sq;
    }
  }
}

extern "C" void kernel_launch(void* const* d_in, const int* in_sizes, int n_in,
                              void* d_out, int out_size, void* d_ws, size_t ws_size,
                              hipStream_t stream) {
  const void* x  = d_in[0];
  const void* W1 = d_in[1];
  const void* b1 = d_in[2];
  const void* W2 = d_in[3];
  const void* b2 = d_in[4];
  const void* W3 = d_in[5];
  const void* b3 = d_in[6];

  const int NR = 8192, DIN = 1024, DH = 4096, DOUT = 1024;

  char* ws = (char*)d_ws;
  size_t off = 0;
  int* mode = (int*)(ws + off);                        off += 256;
  unsigned short* W1b = (unsigned short*)(ws + off);   off += (size_t)DH * DIN * 2;
  unsigned short* W2b = (unsigned short*)(ws + off);   off += (size_t)DH * DH * 2;
  unsigned short* W3b = (unsigned short*)(ws + off);   off += (size_t)DOUT * DH * 2;
  unsigned short* xb  = (unsigned short*)(ws + off);   off += (size_t)NR * DIN * 2;
  unsigned short* y1  = (unsigned short*)(ws + off);   off += (size_t)NR * DH * 2;
  unsigned short* y2  = (unsigned short*)(ws + off);   off += (size_t)NR * DH * 2;
  unsigned short* y3  = (unsigned short*)(ws + off);   off += (size_t)NR * DOUT * 2;
  float* part1 = (float*)(ws + off);                   off += (size_t)NR * 64 * 4;
  float* part2 = (float*)(ws + off);                   off += (size_t)NR * 64 * 4;
  float* part3 = (float*)(ws + off);                   off += (size_t)NR * 16 * 4;
  float* sc0  = (float*)(ws + off);                    off += (size_t)NR * 4;
  float* x0c  = (float*)(ws + off);                    off += (size_t)NR * 4;
  float* sc1  = (float*)(ws + off);                    off += (size_t)NR * 4;
  float* c01  = (float*)(ws + off);                    off += (size_t)NR * 4;
  float* sc2  = (float*)(ws + off);                    off += (size_t)NR * 4;
  float* c02  = (float*)(ws + off);                    off += (size_t)NR * 4;
  float* ss3  = (float*)(ws + off);                    off += (size_t)NR * 4;
  float* w1c0 = (float*)(ws + off);                    off += (size_t)DH * 4;
  float* w2c0 = (float*)(ws + off);                    off += (size_t)DH * 4;
  float* w3c0 = (float*)(ws + off);                    off += (size_t)DOUT * 4;
  float* b1f  = (float*)(ws + off);                    off += (size_t)DH * 4;
  float* b2f  = (float*)(ws + off);                    off += (size_t)DH * 4;
  float* b3f  = (float*)(ws + off);                    off += (size_t)DOUT * 4;

  k_sniff<<<1, 64, 0, stream>>>((const unsigned short*)x, mode);

  k_cvtb<<<16, 256, 0, stream>>>(b1, b2, b3, b1f, b2f, b3f, mode);
  k_cvtw<128><<<(DH * DIN / 8 + 255) / 256, 256, 0, stream>>>(W1, W1b, mode, DH * DIN / 8, w1c0);
  k_cvtw<512><<<(DH * DH  / 8 + 255) / 256, 256, 0, stream>>>(W2, W2b, mode, DH * DH / 8, w2c0);
  k_cvtw<512><<<(DOUT * DH / 8 + 255) / 256, 256, 0, stream>>>(W3, W3b, mode, DOUT * DH / 8, w3c0);

  k_prep<<<NR, 256, 0, stream>>>(x, xb, sc0, x0c, mode);

  k_gemm_bt<4096, 1024, 64><<<dim3(DH / 128, NR / 128), 256, 0, stream>>>(
      xb, W1b, b1f, sc0, x0c, w1c0, y1, part1);
  k_sc<64><<<(NR + 255) / 256, 256, 0, stream>>>(part1, y1, DH, sc1, c01, nullptr, NR);

  k_gemm_bt<4096, 4096, 64><<<dim3(DH / 128, NR / 128), 256, 0, stream>>>(
      y1, W2b, b2f, sc1, c01, w2c0, y2, part2);
  k_sc<64><<<(NR + 255) / 256, 256, 0, stream>>>(part2, y2, DH, sc2, c02, nullptr, NR);

  k_gemm_bt<1024, 4096, 16><<<dim3(DOUT / 128, NR / 128), 256, 0, stream>>>(
      y2, W3b, b3f, sc2, c02, w3c0, y3, part3);
  k_sc<16><<<(NR + 255) / 256, 256, 0, stream>>>(part3, y3, DOUT, sc0, x0c, ss3, NR);

  k_final<<<NR, 256, 0, stream>>>(y3, ss3, d_out, mode);
}

// Round 5
// 674.183 us; speedup vs baseline: 1.0589x; 1.0589x over previous
//
#include <hip/hip_runtime.h>
#include <stdint.h>

#define EPSF 1e-7f
#define MAXTAN 10.0f

typedef __bf16 bf16x8 __attribute__((ext_vector_type(8)));
typedef float floatx4 __attribute__((ext_vector_type(4)));
typedef __attribute__((address_space(3))) void lds_void_t;
typedef __attribute__((address_space(1))) void gbl_void_t;

__device__ __forceinline__ unsigned short f2bf(float x) {
  union { float f; uint32_t u; } v; v.f = x;
  uint32_t u = v.u;
  u += 0x7fffu + ((u >> 16) & 1u);   // RNE
  return (unsigned short)(u >> 16);
}
__device__ __forceinline__ float bf2f(unsigned short h) {
  union { uint32_t u; float f; } v; v.u = ((uint32_t)h) << 16;
  return v.f;
}

__device__ __forceinline__ int sniff_mode(const unsigned short* x) {
  int sane = 0;
  for (int i = 0; i < 128; ++i) {
    unsigned short h = x[i];
    int e = (h >> 7) & 0xFF;
    if ((h & 0x7FFF) == 0 || (e >= 96 && e <= 140)) ++sane;
  }
  return (sane >= 120) ? 1 : 0;
}

// ---------------- init: sniff dtype + convert biases ----------------
__global__ void k_init(const unsigned short* __restrict__ x, int* __restrict__ modeg,
                       const void* __restrict__ b1, const void* __restrict__ b2,
                       const void* __restrict__ b3, float* __restrict__ o1,
                       float* __restrict__ o2, float* __restrict__ o3) {
  __shared__ int mds;
  if (threadIdx.x == 0) {
    int m = sniff_mode(x);
    mds = m;
    if (blockIdx.x == 0) *modeg = m;
  }
  __syncthreads();
  int m = mds;
  int i = blockIdx.x * 256 + threadIdx.x;
  if (i < 4096) o1[i] = m ? bf2f(((const unsigned short*)b1)[i]) : ((const float*)b1)[i];
  if (i < 4096) o2[i] = m ? bf2f(((const unsigned short*)b2)[i]) : ((const float*)b2)[i];
  if (i < 1024) o3[i] = m ? bf2f(((const unsigned short*)b3)[i]) : ((const float*)b3)[i];
}

// ---------------- x prep: convert to bf16, compute logmap scale + x0 ----------------
__global__ void k_prep(const void* __restrict__ xv, unsigned short* __restrict__ xb,
                       float* __restrict__ sc0, float* __restrict__ x0c,
                       const int* __restrict__ mode) {
  const int row = blockIdx.x;
  const int tid = threadIdx.x;
  float4 v;
  if (*mode) {
    ushort4 u = ((const ushort4*)((const unsigned short*)xv + (size_t)row * 1024))[tid];
    v.x = bf2f(u.x); v.y = bf2f(u.y); v.z = bf2f(u.z); v.w = bf2f(u.w);
  } else {
    v = ((const float4*)((const float*)xv + (size_t)row * 1024))[tid];
  }
  ushort4 o;
  o.x = f2bf(v.x); o.y = f2bf(v.y); o.z = f2bf(v.z); o.w = f2bf(v.w);
  ((ushort4*)(xb + (size_t)row * 1024))[tid] = o;

  float s = v.x * v.x + v.y * v.y + v.z * v.z + v.w * v.w;
  if (tid == 0) s -= v.x * v.x;          // exclude time coordinate
  for (int off = 32; off; off >>= 1) s += __shfl_down(s, off, 64);
  __shared__ float red[4];
  if ((tid & 63) == 0) red[tid >> 6] = s;
  __syncthreads();
  if (tid == 0) {
    s = red[0] + red[1] + red[2] + red[3];
    float ns = fmaxf(sqrtf(s), EPSF);
    float d = acoshf(fmaxf(v.x, 1.0f + EPSF));
    sc0[row] = d / ns;
    x0c[row] = bf2f(o.x);
  }
}

// ---------------- weight convert to bf16 + col0 extraction ----------------
template<int K8>
__global__ void k_cvtw(const void* __restrict__ in, unsigned short* __restrict__ out,
                       const int* __restrict__ mode, int n8, float* __restrict__ c0) {
  int i = blockIdx.x * 256 + threadIdx.x;
  if (i >= n8) return;
  if (*mode) {
    uint4 g = ((const uint4*)in)[i];
    ((uint4*)out)[i] = g;
    if (i % K8 == 0) c0[i / K8] = bf2f((unsigned short)(g.x & 0xFFFFu));
  } else {
    float4 a = ((const float4*)in)[2 * i];
    float4 b = ((const float4*)in)[2 * i + 1];
    ushort4 oa, ob;
    oa.x = f2bf(a.x); oa.y = f2bf(a.y); oa.z = f2bf(a.z); oa.w = f2bf(a.w);
    ob.x = f2bf(b.x); ob.y = f2bf(b.y); ob.z = f2bf(b.z); ob.w = f2bf(b.w);
    ((ushort4*)out)[2 * i] = oa;
    ((ushort4*)out)[2 * i + 1] = ob;
    if (i % K8 == 0) c0[i / K8] = bf2f(oa.x);
  }
}

// ---------------- partial-sumsq fold -> scale + col0 grab ----------------
template<int NBLK>
__global__ void k_sc(const float* __restrict__ part, const unsigned short* __restrict__ y,
                     int stride, float* __restrict__ sc, float* __restrict__ c0,
                     float* __restrict__ ssout, int nrows) {
  int i = blockIdx.x * 256 + threadIdx.x;
  if (i >= nrows) return;
  float s = 0.f;
#pragma unroll
  for (int j = 0; j < NBLK; ++j) s += part[(size_t)i * NBLK + j];
  float n = fmaxf(sqrtf(fmaxf(s, 0.f)), EPSF);
  sc[i] = fminf(n, MAXTAN) / n;
  c0[i] = bf2f(y[(size_t)i * stride]);
  if (ssout) ssout[i] = s;
}

// ---------------- final: y3 bf16 + ss3 -> projx(safe_expmap0(y3)) ----------------
__global__ void k_final(const unsigned short* __restrict__ y, const float* __restrict__ ss,
                        void* __restrict__ outv, const int* __restrict__ mode) {
  const int row = blockIdx.x;
  const int tid = threadIdx.x;
  float n = fmaxf(sqrtf(fmaxf(ss[row], 0.f)), EPSF);
  float nc = fminf(n, MAXTAN);
  float a = sinhf(nc) / n;
  ushort4 u = ((const ushort4*)(y + (size_t)row * 1024))[tid];
  float4 o;
  o.x = bf2f(u.x) * a; o.y = bf2f(u.y) * a;
  o.z = bf2f(u.z) * a; o.w = bf2f(u.w) * a;
  if (tid == 0) o.x = coshf(nc);
  if (*mode) {
    ushort4 o16;
    o16.x = f2bf(o.x); o16.y = f2bf(o.y); o16.z = f2bf(o.z); o16.w = f2bf(o.w);
    ((ushort4*)outv)[(size_t)row * 256 + tid] = o16;
  } else {
    ((float4*)outv)[(size_t)row * 256 + tid] = o;
  }
}

// ---------------- NT GEMM, BK=32, fused rank-1 epilogue, XCD-swizzled grid ----------------
// Launched 1D (GX*GY blocks). Block i -> XCD patch j=i&7: 16x16 patches (GX=32)
// or 8x8 patches (GX=8), so each XCD's resident blocks tile a compact sub-grid
// (fewer distinct A/B K-slabs per XCD L2 -> less HBM replication).
// y[m,n] = sc[m]*(acc[m,n] - c0f[m]*wc0[n]) + bias[n], stored bf16.
// Per-(row,wave) sumsq partials -> part[gm*NBLK + 2*bx + (wave&1)] (no atomics).
// LDS swizzle (measured 0 conflicts): granule g of row r holds global granule g ^ ((r>>1)&3).
template<int N, int K, int NBLK, int GX>
__global__ __launch_bounds__(256, 4) void k_gemm_bt(
    const unsigned short* __restrict__ A,
    const unsigned short* __restrict__ B,
    const float* __restrict__ bias,
    const float* __restrict__ sc,
    const float* __restrict__ c0f,
    const float* __restrict__ wc0,
    unsigned short* __restrict__ Cb,
    float* __restrict__ part)
{
  __shared__ __align__(16) unsigned short As[128 * 32];
  __shared__ __align__(16) unsigned short Bs[128 * 32];

  const int tid  = threadIdx.x;
  const int wave = tid >> 6;
  const int lane = tid & 63;
  const int quad = lane >> 4;
  const int m16  = lane & 15;

  // XCD-aware block swizzle
  const int j = blockIdx.x & 7;
  const int k = blockIdx.x >> 3;
  int bxi, byi;
  if (GX == 32) {            // 2x4 patches of 16x16
    bxi = 16 * (j & 1) + (k & 15);
    byi = 16 * (j >> 1) + (k >> 4);
  } else {                   // GX == 8: 8 patches of 8x8 stacked in y
    bxi = k & 7;
    byi = 8 * j + (k >> 3);
  }
  const int bm = byi * 128;
  const int bn = bxi * 128;

  const int srow = lane >> 2;                                // 0..15 row within chunk
  const int scol = (((lane & 3) ^ ((srow >> 1) & 3)) << 3);  // swizzled granule (elems)

  const int wm = (wave >> 1) << 6;
  const int wn = (wave & 1) << 6;

  const int rsw = ((quad ^ ((m16 >> 1) & 3)) << 3);          // read-side swizzle

  // bumped staging pointers (keeps per-iter VALU + register count low)
  const int c0i = wave * 2;
  const unsigned short* ga0 = A + (size_t)(bm + c0i * 16 + srow) * K + scol;
  const unsigned short* ga1 = ga0 + (size_t)16 * K;
  const unsigned short* gb0 = B + (size_t)(bn + c0i * 16 + srow) * K + scol;
  const unsigned short* gb1 = gb0 + (size_t)16 * K;

  floatx4 acc[4][4];
#pragma unroll
  for (int i = 0; i < 4; ++i)
#pragma unroll
    for (int jj = 0; jj < 4; ++jj)
#pragma unroll
      for (int r = 0; r < 4; ++r) acc[i][jj][r] = 0.0f;

  for (int k0 = 0; k0 < K; k0 += 32) {
    __builtin_amdgcn_global_load_lds((gbl_void_t*)(void*)ga0,
                                     (lds_void_t*)(As + c0i * 512), 16, 0, 0);
    __builtin_amdgcn_global_load_lds((gbl_void_t*)(void*)ga1,
                                     (lds_void_t*)(As + c0i * 512 + 512), 16, 0, 0);
    __builtin_amdgcn_global_load_lds((gbl_void_t*)(void*)gb0,
                                     (lds_void_t*)(Bs + c0i * 512), 16, 0, 0);
    __builtin_amdgcn_global_load_lds((gbl_void_t*)(void*)gb1,
                                     (lds_void_t*)(Bs + c0i * 512 + 512), 16, 0, 0);
    ga0 += 32; ga1 += 32; gb0 += 32; gb1 += 32;
    __syncthreads();

    bf16x8 af[4], bfg[4];
#pragma unroll
    for (int t = 0; t < 4; ++t) {
      af[t]  = *(const bf16x8*)(As + (wm + t * 16 + m16) * 32 + rsw);
      bfg[t] = *(const bf16x8*)(Bs + (wn + t * 16 + m16) * 32 + rsw);
    }
#pragma unroll
    for (int mt = 0; mt < 4; ++mt)
#pragma unroll
      for (int nt = 0; nt < 4; ++nt)
        acc[mt][nt] = __builtin_amdgcn_mfma_f32_16x16x32_bf16(af[mt], bfg[nt], acc[mt][nt], 0, 0, 0);
    __syncthreads();
  }

  // epilogue: C/D layout col = lane&15, row = quad*4 + r
#pragma unroll
  for (int mt = 0; mt < 4; ++mt) {
#pragma unroll
    for (int r = 0; r < 4; ++r) {
      const int gm = bm + wm + mt * 16 + quad * 4 + r;
      const float scv = sc[gm];
      const float c0v = c0f[gm];
      float sq = 0.f;
#pragma unroll
      for (int nt = 0; nt < 4; ++nt) {
        const int gn = bn + wn + nt * 16 + m16;
        float v = scv * (acc[mt][nt][r] - c0v * wc0[gn]) + bias[gn];
        Cb[(size_t)gm * N + gn] = f2bf(v);
        sq += (gn == 0) ? 0.f : v * v;
      }
      sq += __shfl_xor(sq, 1, 64);
      sq += __shfl_xor(sq, 2, 64);
      sq += __shfl_xor(sq, 4, 64);
      sq += __shfl_xor(sq, 8, 64);
      if (m16 == 0) part[(size_t)gm * NBLK + 2 * bxi + (wave & 1)] = sq;
    }
  }
}

extern "C" void kernel_launch(void* const* d_in, const int* in_sizes, int n_in,
                              void* d_out, int out_size, void* d_ws, size_t ws_size,
                              hipStream_t stream) {
  const void* x  = d_in[0];
  const void* W1 = d_in[1];
  const void* b1 = d_in[2];
  const void* W2 = d_in[3];
  const void* b2 = d_in[4];
  const void* W3 = d_in[5];
  const void* b3 = d_in[6];

  const int NR = 8192, DIN = 1024, DH = 4096, DOUT = 1024;

  char* ws = (char*)d_ws;
  size_t off = 0;
  int* mode = (int*)(ws + off);                        off += 256;
  unsigned short* W1b = (unsigned short*)(ws + off);   off += (size_t)DH * DIN * 2;
  unsigned short* W2b = (unsigned short*)(ws + off);   off += (size_t)DH * DH * 2;
  unsigned short* W3b = (unsigned short*)(ws + off);   off += (size_t)DOUT * DH * 2;
  unsigned short* xb  = (unsigned short*)(ws + off);   off += (size_t)NR * DIN * 2;
  unsigned short* y1  = (unsigned short*)(ws + off);   off += (size_t)NR * DH * 2;
  unsigned short* y2  = (unsigned short*)(ws + off);   off += (size_t)NR * DH * 2;
  unsigned short* y3  = (unsigned short*)(ws + off);   off += (size_t)NR * DOUT * 2;
  float* part1 = (float*)(ws + off);                   off += (size_t)NR * 64 * 4;
  float* part2 = (float*)(ws + off);                   off += (size_t)NR * 64 * 4;
  float* part3 = (float*)(ws + off);                   off += (size_t)NR * 16 * 4;
  float* sc0  = (float*)(ws + off);                    off += (size_t)NR * 4;
  float* x0c  = (float*)(ws + off);                    off += (size_t)NR * 4;
  float* sc1  = (float*)(ws + off);                    off += (size_t)NR * 4;
  float* c01  = (float*)(ws + off);                    off += (size_t)NR * 4;
  float* sc2  = (float*)(ws + off);                    off += (size_t)NR * 4;
  float* c02  = (float*)(ws + off);                    off += (size_t)NR * 4;
  float* ss3  = (float*)(ws + off);                    off += (size_t)NR * 4;
  float* w1c0 = (float*)(ws + off);                    off += (size_t)DH * 4;
  float* w2c0 = (float*)(ws + off);                    off += (size_t)DH * 4;
  float* w3c0 = (float*)(ws + off);                    off += (size_t)DOUT * 4;
  float* b1f  = (float*)(ws + off);                    off += (size_t)DH * 4;
  float* b2f  = (float*)(ws + off);                    off += (size_t)DH * 4;
  float* b3f  = (float*)(ws + off);                    off += (size_t)DOUT * 4;

  k_init<<<16, 256, 0, stream>>>((const unsigned short*)x, mode, b1, b2, b3, b1f, b2f, b3f);

  k_cvtw<128><<<(DH * DIN / 8 + 255) / 256, 256, 0, stream>>>(W1, W1b, mode, DH * DIN / 8, w1c0);
  k_cvtw<512><<<(DH * DH  / 8 + 255) / 256, 256, 0, stream>>>(W2, W2b, mode, DH * DH / 8, w2c0);
  k_cvtw<512><<<(DOUT * DH / 8 + 255) / 256, 256, 0, stream>>>(W3, W3b, mode, DOUT * DH / 8, w3c0);

  k_prep<<<NR, 256, 0, stream>>>(x, xb, sc0, x0c, mode);

  k_gemm_bt<4096, 1024, 64, 32><<<2048, 256, 0, stream>>>(
      xb, W1b, b1f, sc0, x0c, w1c0, y1, part1);
  k_sc<64><<<(NR + 255) / 256, 256, 0, stream>>>(part1, y1, DH, sc1, c01, nullptr, NR);

  k_gemm_bt<4096, 4096, 64, 32><<<2048, 256, 0, stream>>>(
      y1, W2b, b2f, sc1, c01, w2c0, y2, part2);
  k_sc<64><<<(NR + 255) / 256, 256, 0, stream>>>(part2, y2, DH, sc2, c02, nullptr, NR);

  k_gemm_bt<1024, 4096, 16, 8><<<512, 256, 0, stream>>>(
      y2, W3b, b3f, sc2, c02, w3c0, y3, part3);
  k_sc<16><<<(NR + 255) / 256, 256, 0, stream>>>(part3, y3, DOUT, sc0, x0c, ss3, NR);

  k_final<<<NR, 256, 0, stream>>>(y3, ss3, d_out, mode);
}